// Round 1
// baseline (8828.385 us; speedup 1.0000x reference)
//
#include <hip/hip_runtime.h>
#include <cstddef>

// GCN1: 3x (GCNConv -> BatchNorm -> ReLU[layers 1,2]) on N=100k nodes, E=800k edges.
// Round 1: correctness-first fp32 baseline.
//  - aggregate-first for layer 1 (128 cols), aggregate-last for layer 3 (40 cols)
//  - biases skipped: BN(h+b) == BN(h) (shift-invariant), and b==0 anyway
//  - f32 atomicAdd edge aggregation (CSR no-atomic version is a later round)
//  - simple 64x64 LDS-tiled fp32 GEMM (bf16 MFMA is a later round)

#define NN 100000
#define NE 800000
#define FIN 128
#define HIDD 512
#define NCLS 40
#define BN_EPS 1e-5f

static inline int ceil_div_ll(long long a, long long b) { return (int)((a + b - 1) / b); }

// ---------------- degree / dinv ----------------
__global__ void deg_kernel(const int* __restrict__ dst, float* __restrict__ deg) {
    int e = blockIdx.x * 256 + threadIdx.x;
    if (e < NE) atomicAdd(&deg[dst[e]], 1.0f);
}

__global__ void dinv_kernel(float* __restrict__ deg) {
    int i = blockIdx.x * 256 + threadIdx.x;
    if (i < NN) deg[i] = rsqrtf(deg[i] + 1.0f);
}

// ---------------- aggregation ----------------
// out[i][:] = h[i][:] * dinv[i]^2   (self-loop term; also serves as the zero-init)
template<int C>
__global__ void self_init_kernel(const float* __restrict__ h, const float* __restrict__ dinv,
                                 float* __restrict__ out) {
    const long long TOT = (long long)NN * (C / 4);
    long long i = (long long)blockIdx.x * 256 + threadIdx.x;
    if (i >= TOT) return;
    int node = (int)(i / (C / 4));
    float di = dinv[node];
    float s = di * di;
    float4 v = reinterpret_cast<const float4*>(h)[i];
    v.x *= s; v.y *= s; v.z *= s; v.w *= s;
    reinterpret_cast<float4*>(out)[i] = v;
}

// out[dst][:] += h[src][:] * dinv[src]*dinv[dst]   via f32 atomics
template<int C>
__global__ void agg_edges_kernel(const float* __restrict__ h, const int* __restrict__ src,
                                 const int* __restrict__ dst, const float* __restrict__ dinv,
                                 float* __restrict__ out) {
    constexpr int TPE = C / 4;  // threads per edge, float4 each
    long long g = (long long)blockIdx.x * 256 + threadIdx.x;
    if (g >= (long long)NE * TPE) return;
    int e = (int)(g / TPE);
    int c = (int)(g % TPE);
    int s = src[e];
    int d = dst[e];
    float nrm = dinv[s] * dinv[d];
    float4 v = reinterpret_cast<const float4*>(h + (size_t)s * C)[c];
    float* o = out + (size_t)d * C + (size_t)c * 4;
    atomicAdd(o + 0, v.x * nrm);
    atomicAdd(o + 1, v.y * nrm);
    atomicAdd(o + 2, v.z * nrm);
    atomicAdd(o + 3, v.w * nrm);
}

// ---------------- fp32 GEMM: C[N,M] = A[N,K] @ B[K,M] ----------------
// 64x64 tile, BK=16, 256 threads, 4x4 micro-tile per thread.
__global__ __launch_bounds__(256) void gemm_kernel(const float* __restrict__ A,
                                                   const float* __restrict__ B,
                                                   float* __restrict__ C,
                                                   int N, int K, int M) {
    __shared__ float As[16][64];
    __shared__ float Bs[16][64];
    const int tid = threadIdx.x;
    const int m0 = blockIdx.y * 64;
    const int n0 = blockIdx.x * 64;
    const int tx = tid & 15;
    const int ty = tid >> 4;
    float acc[4][4] = {};

    for (int k0 = 0; k0 < K; k0 += 16) {
        // A tile: 64 rows x 16 k (float4 along k)
        {
            int r = tid >> 2;
            int kq = (tid & 3) * 4;
            int row = m0 + r;
            float4 a = make_float4(0.f, 0.f, 0.f, 0.f);
            if (row < N) a = *reinterpret_cast<const float4*>(A + (size_t)row * K + k0 + kq);
            As[kq + 0][r] = a.x; As[kq + 1][r] = a.y; As[kq + 2][r] = a.z; As[kq + 3][r] = a.w;
        }
        // B tile: 16 k x 64 n (float4 along n)
        {
            int kk = tid >> 4;
            int nq = (tid & 15) * 4;
            int col = n0 + nq;
            float4 b = make_float4(0.f, 0.f, 0.f, 0.f);
            if (col + 3 < M) b = *reinterpret_cast<const float4*>(B + (size_t)(k0 + kk) * M + col);
            *reinterpret_cast<float4*>(&Bs[kk][nq]) = b;
        }
        __syncthreads();
        #pragma unroll
        for (int k = 0; k < 16; ++k) {
            float4 a4 = *reinterpret_cast<const float4*>(&As[k][ty * 4]);
            float4 b4 = *reinterpret_cast<const float4*>(&Bs[k][tx * 4]);
            float av[4] = {a4.x, a4.y, a4.z, a4.w};
            float bv[4] = {b4.x, b4.y, b4.z, b4.w};
            #pragma unroll
            for (int i = 0; i < 4; ++i)
                #pragma unroll
                for (int j = 0; j < 4; ++j)
                    acc[i][j] += av[i] * bv[j];
        }
        __syncthreads();
    }

    #pragma unroll
    for (int i = 0; i < 4; ++i) {
        int row = m0 + ty * 4 + i;
        if (row >= N) continue;
        #pragma unroll
        for (int j = 0; j < 4; ++j) {
            int col = n0 + tx * 4 + j;
            if (col < M) C[(size_t)row * M + col] = acc[i][j];
        }
    }
}

// ---------------- BatchNorm ----------------
__global__ void colstats_kernel(const float* __restrict__ X, int C, int rows_per_block,
                                float* __restrict__ colsum, float* __restrict__ colsumsq) {
    int col = blockIdx.y * 256 + threadIdx.x;
    if (col >= C) return;
    int r0 = blockIdx.x * rows_per_block;
    int r1 = min(r0 + rows_per_block, NN);
    float s = 0.f, ss = 0.f;
    for (int r = r0; r < r1; ++r) {
        float v = X[(size_t)r * C + col];
        s += v;
        ss += v * v;
    }
    atomicAdd(&colsum[col], s);
    atomicAdd(&colsumsq[col], ss);
}

__global__ void finalize_stats_kernel(const float* __restrict__ colsum,
                                      const float* __restrict__ colsumsq,
                                      float* __restrict__ meanv, float* __restrict__ rstdv,
                                      int C) {
    int c = blockIdx.x * 256 + threadIdx.x;
    if (c >= C) return;
    float mu = colsum[c] * (1.0f / NN);
    float var = colsumsq[c] * (1.0f / NN) - mu * mu;
    meanv[c] = mu;
    rstdv[c] = rsqrtf(var + BN_EPS);
}

template<bool RELU, int C>
__global__ void bn_apply_kernel(const float* __restrict__ X, float* __restrict__ Y,
                                const float* __restrict__ meanv, const float* __restrict__ rstdv,
                                const float* __restrict__ g, const float* __restrict__ be) {
    const long long TOT = (long long)NN * (C / 4);
    long long i = (long long)blockIdx.x * 256 + threadIdx.x;
    if (i >= TOT) return;
    int c = (int)((i % (C / 4)) * 4);
    float4 v = reinterpret_cast<const float4*>(X)[i];
    float r[4] = {v.x, v.y, v.z, v.w};
    float o[4];
    #pragma unroll
    for (int j = 0; j < 4; ++j) {
        float y = g[c + j] * (r[j] - meanv[c + j]) * rstdv[c + j] + be[c + j];
        if (RELU) y = fmaxf(y, 0.f);
        o[j] = y;
    }
    reinterpret_cast<float4*>(Y)[i] = make_float4(o[0], o[1], o[2], o[3]);
}

// ---------------- orchestration ----------------
extern "C" void kernel_launch(void* const* d_in, const int* in_sizes, int n_in,
                              void* d_out, int out_size, void* d_ws, size_t ws_size,
                              hipStream_t stream) {
    const float* x   = (const float*)d_in[0];
    const int*   ei  = (const int*)d_in[1];
    const float* W1  = (const float*)d_in[2];
    const float* g1  = (const float*)d_in[4];
    const float* be1 = (const float*)d_in[5];
    const float* W2  = (const float*)d_in[6];
    const float* g2  = (const float*)d_in[8];
    const float* be2 = (const float*)d_in[9];
    const float* W3  = (const float*)d_in[10];
    const float* g3  = (const float*)d_in[12];
    const float* be3 = (const float*)d_in[13];

    const int* src = ei;
    const int* dst = ei + NE;

    float* out = (float*)d_out;                 // [NN, 40]
    float* x6  = out + (size_t)NN * NCLS;       // [NN, 512] second output, staged in place

    float* W = (float*)d_ws;
    float* dinv     = W;                                   // NN
    float* colsum   = W + 100352;                          // 512
    float* colsumsq = colsum + 512;                        // 512
    float* meanv    = colsumsq + 512;                      // 512
    float* rstdv    = meanv + 512;                         // 512
    float* aggX1    = W + 100352 + 4096;                   // NN*128
    float* bufA     = aggX1 + (size_t)NN * FIN;            // NN*512
    float* bufB     = bufA + (size_t)NN * HIDD;            // NN*512
    float* bufH3    = aggX1;                               // reuse (NN*40)
    float* agg3     = aggX1 + (size_t)NN * NCLS;           // NN*40

    const int B = 256;
    // --- degrees (shared by all layers) ---
    hipMemsetAsync(dinv, 0, (size_t)NN * 4, stream);
    deg_kernel<<<ceil_div_ll(NE, B), B, 0, stream>>>(dst, dinv);
    dinv_kernel<<<ceil_div_ll(NN, B), B, 0, stream>>>(dinv);

    // --- layer 1: agg(x) -> GEMM(128x512) -> BN -> relu ---
    self_init_kernel<FIN><<<ceil_div_ll((long long)NN * FIN / 4, B), B, 0, stream>>>(x, dinv, aggX1);
    agg_edges_kernel<FIN><<<ceil_div_ll((long long)NE * FIN / 4, B), B, 0, stream>>>(x, src, dst, dinv, aggX1);
    {
        dim3 grid(HIDD / 64, ceil_div_ll(NN, 64));
        gemm_kernel<<<grid, B, 0, stream>>>(aggX1, W1, bufA, NN, FIN, HIDD);
    }
    hipMemsetAsync(colsum, 0, 1024 * 4, stream);
    {
        dim3 grid(ceil_div_ll(NN, 128), 2);
        colstats_kernel<<<grid, B, 0, stream>>>(bufA, HIDD, 128, colsum, colsumsq);
    }
    finalize_stats_kernel<<<2, B, 0, stream>>>(colsum, colsumsq, meanv, rstdv, HIDD);
    bn_apply_kernel<true, HIDD><<<ceil_div_ll((long long)NN * HIDD / 4, B), B, 0, stream>>>(
        bufA, bufA, meanv, rstdv, g1, be1);  // bufA = x3

    // --- layer 2: agg(x3) -> GEMM(512x512) -> BN -> relu -> x6 (in d_out) ---
    self_init_kernel<HIDD><<<ceil_div_ll((long long)NN * HIDD / 4, B), B, 0, stream>>>(bufA, dinv, bufB);
    agg_edges_kernel<HIDD><<<ceil_div_ll((long long)NE * HIDD / 4, B), B, 0, stream>>>(bufA, src, dst, dinv, bufB);
    {
        dim3 grid(HIDD / 64, ceil_div_ll(NN, 64));
        gemm_kernel<<<grid, B, 0, stream>>>(bufB, W2, bufA, NN, HIDD, HIDD);
    }
    hipMemsetAsync(colsum, 0, 1024 * 4, stream);
    {
        dim3 grid(ceil_div_ll(NN, 128), 2);
        colstats_kernel<<<grid, B, 0, stream>>>(bufA, HIDD, 128, colsum, colsumsq);
    }
    finalize_stats_kernel<<<2, B, 0, stream>>>(colsum, colsumsq, meanv, rstdv, HIDD);
    bn_apply_kernel<true, HIDD><<<ceil_div_ll((long long)NN * HIDD / 4, B), B, 0, stream>>>(
        bufA, x6, meanv, rstdv, g2, be2);  // x6 written directly to d_out

    // --- layer 3: GEMM(512x40) -> agg -> BN (no relu) ---
    {
        dim3 grid(1, ceil_div_ll(NN, 64));
        gemm_kernel<<<grid, B, 0, stream>>>(x6, W3, bufH3, NN, HIDD, NCLS);
    }
    self_init_kernel<NCLS><<<ceil_div_ll((long long)NN * NCLS / 4, B), B, 0, stream>>>(bufH3, dinv, agg3);
    agg_edges_kernel<NCLS><<<ceil_div_ll((long long)NE * NCLS / 4, B), B, 0, stream>>>(bufH3, src, dst, dinv, agg3);
    hipMemsetAsync(colsum, 0, 1024 * 4, stream);
    {
        dim3 grid(ceil_div_ll(NN, 128), 1);
        colstats_kernel<<<grid, B, 0, stream>>>(agg3, NCLS, 128, colsum, colsumsq);
    }
    finalize_stats_kernel<<<1, B, 0, stream>>>(colsum, colsumsq, meanv, rstdv, NCLS);
    bn_apply_kernel<false, NCLS><<<ceil_div_ll((long long)NN * NCLS / 4, B), B, 0, stream>>>(
        agg3, out, meanv, rstdv, g3, be3);
}

// Round 2
// 2126.080 us; speedup vs baseline: 4.1524x; 4.1524x over previous
//
#include <hip/hip_runtime.h>
#include <cstddef>

// GCN1: 3x (GCNConv -> BatchNorm -> ReLU[layers 1,2]) on N=100k nodes, E=800k edges.
// Round 2: CSR (counting-sort by dst) aggregation — no f32 atomics, no 4x write
// amplification. Wave-per-node register accumulation, self-loop folded in.
//  - aggregate-first for layer 1 (128 cols), aggregate-last for layer 3 (40 cols)
//  - biases skipped: BN(h+b) == BN(h) (shift-invariant), and b==0 anyway
//  - fp32 GEMM unchanged this round (next target: bf16 MFMA)

#define NN 100000
#define NE 800000
#define FIN 128
#define HIDD 512
#define NCLS 40
#define BN_EPS 1e-5f

static inline int ceil_div_ll(long long a, long long b) { return (int)((a + b - 1) / b); }

// ---------------- CSR build ----------------
__global__ void deg_int_kernel(const int* __restrict__ dst, int* __restrict__ degi) {
    int e = blockIdx.x * 256 + threadIdx.x;
    if (e < NE) atomicAdd(&degi[dst[e]], 1);
}

__global__ void dinv_from_deg_kernel(const int* __restrict__ degi, float* __restrict__ dinv) {
    int i = blockIdx.x * 256 + threadIdx.x;
    if (i < NN) dinv[i] = rsqrtf((float)degi[i] + 1.0f);
}

// per-block exclusive scan of degi -> rowptr (partial), block totals -> bsum
__global__ void scan_block_kernel(const int* __restrict__ degi, int* __restrict__ rowptr,
                                  int* __restrict__ bsum) {
    __shared__ int tmp[256];
    int t = threadIdx.x;
    int i = blockIdx.x * 256 + t;
    int v = (i < NN) ? degi[i] : 0;
    tmp[t] = v;
    __syncthreads();
    #pragma unroll
    for (int off = 1; off < 256; off <<= 1) {
        int u = (t >= off) ? tmp[t - off] : 0;
        __syncthreads();
        tmp[t] += u;
        __syncthreads();
    }
    if (i < NN) rowptr[i] = tmp[t] - v;  // exclusive, pre-offset
    if (t == 255) bsum[blockIdx.x] = tmp[255];
}

// single-block exclusive scan of the 391 block sums
__global__ void scan_bsum_kernel(const int* __restrict__ bsum, int* __restrict__ boff, int nb) {
    __shared__ int tmp[512];
    int t = threadIdx.x;
    int v = (t < nb) ? bsum[t] : 0;
    tmp[t] = v;
    __syncthreads();
    #pragma unroll
    for (int off = 1; off < 512; off <<= 1) {
        int u = (t >= off) ? tmp[t - off] : 0;
        __syncthreads();
        tmp[t] += u;
        __syncthreads();
    }
    if (t < nb) boff[t] = tmp[t] - v;  // exclusive
}

__global__ void add_offsets_kernel(int* __restrict__ rowptr, const int* __restrict__ boff,
                                   int* __restrict__ cursor) {
    int i = blockIdx.x * 256 + threadIdx.x;
    if (i < NN) {
        int r = rowptr[i] + boff[i >> 8];
        rowptr[i] = r;
        cursor[i] = r;
    }
}

// scatter edges into CSR order; store (src, dinv[src]) per slot
__global__ void scatter_kernel(const int* __restrict__ src, const int* __restrict__ dst,
                               const float* __restrict__ dinv, int* __restrict__ cursor,
                               int* __restrict__ csr_src, float* __restrict__ csr_w) {
    int e = blockIdx.x * 256 + threadIdx.x;
    if (e >= NE) return;
    int s = src[e];
    int d = dst[e];
    int pos = atomicAdd(&cursor[d], 1);
    csr_src[pos] = s;
    csr_w[pos] = dinv[s];
}

// ---------------- CSR aggregation: wave per node ----------------
// out[d] = dinv[d] * sum_e( dinv[src_e] * h[src_e] ) + dinv[d]^2 * h[d]
__global__ __launch_bounds__(256) void agg_csr512_kernel(
        const float* __restrict__ h, const int* __restrict__ rowptr,
        const int* __restrict__ degi, const float* __restrict__ dinv,
        const int* __restrict__ csr_src, const float* __restrict__ csr_w,
        float* __restrict__ out) {
    int wid = (blockIdx.x * 256 + threadIdx.x) >> 6;  // node id (wave-per-node)
    int lane = threadIdx.x & 63;
    if (wid >= NN) return;
    int r0 = rowptr[wid];
    int n = degi[wid];
    float di = dinv[wid];
    float4 a0 = make_float4(0.f, 0.f, 0.f, 0.f);
    float4 a1 = make_float4(0.f, 0.f, 0.f, 0.f);
    for (int j = 0; j < n; ++j) {
        int s = csr_src[r0 + j];
        float w = csr_w[r0 + j];
        const float4* row = reinterpret_cast<const float4*>(h + (size_t)s * HIDD);
        float4 v0 = row[lane];
        float4 v1 = row[64 + lane];
        a0.x += w * v0.x; a0.y += w * v0.y; a0.z += w * v0.z; a0.w += w * v0.w;
        a1.x += w * v1.x; a1.y += w * v1.y; a1.z += w * v1.z; a1.w += w * v1.w;
    }
    const float4* self = reinterpret_cast<const float4*>(h + (size_t)wid * HIDD);
    float4 s0 = self[lane];
    float4 s1 = self[64 + lane];
    float sq = di * di;
    float4 o0, o1;
    o0.x = di * a0.x + sq * s0.x; o0.y = di * a0.y + sq * s0.y;
    o0.z = di * a0.z + sq * s0.z; o0.w = di * a0.w + sq * s0.w;
    o1.x = di * a1.x + sq * s1.x; o1.y = di * a1.y + sq * s1.y;
    o1.z = di * a1.z + sq * s1.z; o1.w = di * a1.w + sq * s1.w;
    float4* op = reinterpret_cast<float4*>(out + (size_t)wid * HIDD);
    op[lane] = o0;
    op[64 + lane] = o1;
}

__global__ __launch_bounds__(256) void agg_csr128_kernel(
        const float* __restrict__ h, const int* __restrict__ rowptr,
        const int* __restrict__ degi, const float* __restrict__ dinv,
        const int* __restrict__ csr_src, const float* __restrict__ csr_w,
        float* __restrict__ out) {
    int wid = (blockIdx.x * 256 + threadIdx.x) >> 6;
    int lane = threadIdx.x & 63;
    if (wid >= NN) return;
    int r0 = rowptr[wid];
    int n = degi[wid];
    float di = dinv[wid];
    float2 a = make_float2(0.f, 0.f);
    for (int j = 0; j < n; ++j) {
        int s = csr_src[r0 + j];
        float w = csr_w[r0 + j];
        float2 v = reinterpret_cast<const float2*>(h + (size_t)s * FIN)[lane];
        a.x += w * v.x; a.y += w * v.y;
    }
    float2 sv = reinterpret_cast<const float2*>(h + (size_t)wid * FIN)[lane];
    float sq = di * di;
    float2 o;
    o.x = di * a.x + sq * sv.x;
    o.y = di * a.y + sq * sv.y;
    reinterpret_cast<float2*>(out + (size_t)wid * FIN)[lane] = o;
}

__global__ __launch_bounds__(256) void agg_csr40_kernel(
        const float* __restrict__ h, const int* __restrict__ rowptr,
        const int* __restrict__ degi, const float* __restrict__ dinv,
        const int* __restrict__ csr_src, const float* __restrict__ csr_w,
        float* __restrict__ out) {
    int wid = (blockIdx.x * 256 + threadIdx.x) >> 6;
    int lane = threadIdx.x & 63;
    if (wid >= NN) return;
    int r0 = rowptr[wid];
    int n = degi[wid];
    float di = dinv[wid];
    float4 a = make_float4(0.f, 0.f, 0.f, 0.f);
    if (lane < 10) {
        for (int j = 0; j < n; ++j) {
            int s = csr_src[r0 + j];
            float w = csr_w[r0 + j];
            float4 v = reinterpret_cast<const float4*>(h + (size_t)s * NCLS)[lane];
            a.x += w * v.x; a.y += w * v.y; a.z += w * v.z; a.w += w * v.w;
        }
        float4 sv = reinterpret_cast<const float4*>(h + (size_t)wid * NCLS)[lane];
        float sq = di * di;
        float4 o;
        o.x = di * a.x + sq * sv.x; o.y = di * a.y + sq * sv.y;
        o.z = di * a.z + sq * sv.z; o.w = di * a.w + sq * sv.w;
        reinterpret_cast<float4*>(out + (size_t)wid * NCLS)[lane] = o;
    }
}

// ---------------- fp32 GEMM: C[N,M] = A[N,K] @ B[K,M] ----------------
__global__ __launch_bounds__(256) void gemm_kernel(const float* __restrict__ A,
                                                   const float* __restrict__ B,
                                                   float* __restrict__ C,
                                                   int N, int K, int M) {
    __shared__ float As[16][64];
    __shared__ float Bs[16][64];
    const int tid = threadIdx.x;
    const int m0 = blockIdx.y * 64;
    const int n0 = blockIdx.x * 64;
    const int tx = tid & 15;
    const int ty = tid >> 4;
    float acc[4][4] = {};

    for (int k0 = 0; k0 < K; k0 += 16) {
        {
            int r = tid >> 2;
            int kq = (tid & 3) * 4;
            int row = m0 + r;
            float4 a = make_float4(0.f, 0.f, 0.f, 0.f);
            if (row < N) a = *reinterpret_cast<const float4*>(A + (size_t)row * K + k0 + kq);
            As[kq + 0][r] = a.x; As[kq + 1][r] = a.y; As[kq + 2][r] = a.z; As[kq + 3][r] = a.w;
        }
        {
            int kk = tid >> 4;
            int nq = (tid & 15) * 4;
            int col = n0 + nq;
            float4 b = make_float4(0.f, 0.f, 0.f, 0.f);
            if (col + 3 < M) b = *reinterpret_cast<const float4*>(B + (size_t)(k0 + kk) * M + col);
            *reinterpret_cast<float4*>(&Bs[kk][nq]) = b;
        }
        __syncthreads();
        #pragma unroll
        for (int k = 0; k < 16; ++k) {
            float4 a4 = *reinterpret_cast<const float4*>(&As[k][ty * 4]);
            float4 b4 = *reinterpret_cast<const float4*>(&Bs[k][tx * 4]);
            float av[4] = {a4.x, a4.y, a4.z, a4.w};
            float bv[4] = {b4.x, b4.y, b4.z, b4.w};
            #pragma unroll
            for (int i = 0; i < 4; ++i)
                #pragma unroll
                for (int j = 0; j < 4; ++j)
                    acc[i][j] += av[i] * bv[j];
        }
        __syncthreads();
    }

    #pragma unroll
    for (int i = 0; i < 4; ++i) {
        int row = m0 + ty * 4 + i;
        if (row >= N) continue;
        #pragma unroll
        for (int j = 0; j < 4; ++j) {
            int col = n0 + tx * 4 + j;
            if (col < M) C[(size_t)row * M + col] = acc[i][j];
        }
    }
}

// ---------------- BatchNorm ----------------
__global__ void colstats_kernel(const float* __restrict__ X, int C, int rows_per_block,
                                float* __restrict__ colsum, float* __restrict__ colsumsq) {
    int col = blockIdx.y * 256 + threadIdx.x;
    if (col >= C) return;
    int r0 = blockIdx.x * rows_per_block;
    int r1 = min(r0 + rows_per_block, NN);
    float s = 0.f, ss = 0.f;
    for (int r = r0; r < r1; ++r) {
        float v = X[(size_t)r * C + col];
        s += v;
        ss += v * v;
    }
    atomicAdd(&colsum[col], s);
    atomicAdd(&colsumsq[col], ss);
}

__global__ void finalize_stats_kernel(const float* __restrict__ colsum,
                                      const float* __restrict__ colsumsq,
                                      float* __restrict__ meanv, float* __restrict__ rstdv,
                                      int C) {
    int c = blockIdx.x * 256 + threadIdx.x;
    if (c >= C) return;
    float mu = colsum[c] * (1.0f / NN);
    float var = colsumsq[c] * (1.0f / NN) - mu * mu;
    meanv[c] = mu;
    rstdv[c] = rsqrtf(var + BN_EPS);
}

template<bool RELU, int C>
__global__ void bn_apply_kernel(const float* __restrict__ X, float* __restrict__ Y,
                                const float* __restrict__ meanv, const float* __restrict__ rstdv,
                                const float* __restrict__ g, const float* __restrict__ be) {
    const long long TOT = (long long)NN * (C / 4);
    long long i = (long long)blockIdx.x * 256 + threadIdx.x;
    if (i >= TOT) return;
    int c = (int)((i % (C / 4)) * 4);
    float4 v = reinterpret_cast<const float4*>(X)[i];
    float r[4] = {v.x, v.y, v.z, v.w};
    float o[4];
    #pragma unroll
    for (int j = 0; j < 4; ++j) {
        float y = g[c + j] * (r[j] - meanv[c + j]) * rstdv[c + j] + be[c + j];
        if (RELU) y = fmaxf(y, 0.f);
        o[j] = y;
    }
    reinterpret_cast<float4*>(Y)[i] = make_float4(o[0], o[1], o[2], o[3]);
}

// ---------------- orchestration ----------------
extern "C" void kernel_launch(void* const* d_in, const int* in_sizes, int n_in,
                              void* d_out, int out_size, void* d_ws, size_t ws_size,
                              hipStream_t stream) {
    const float* x   = (const float*)d_in[0];
    const int*   ei  = (const int*)d_in[1];
    const float* W1  = (const float*)d_in[2];
    const float* g1  = (const float*)d_in[4];
    const float* be1 = (const float*)d_in[5];
    const float* W2  = (const float*)d_in[6];
    const float* g2  = (const float*)d_in[8];
    const float* be2 = (const float*)d_in[9];
    const float* W3  = (const float*)d_in[10];
    const float* g3  = (const float*)d_in[12];
    const float* be3 = (const float*)d_in[13];

    const int* src = ei;
    const int* dst = ei + NE;

    float* out = (float*)d_out;                 // [NN, 40]
    float* x6  = out + (size_t)NN * NCLS;       // [NN, 512] second output, staged in place

    // workspace layout (floats/ints, 4B each)
    float* W = (float*)d_ws;
    float* dinv     = W;                                    // NN
    int*   degi     = (int*)(W + 100352);                   // NN
    int*   rowptr   = degi + 100352;                        // NN
    int*   cursor   = rowptr + 100352;                      // NN
    int*   bsum     = cursor + 100352;                      // 512
    int*   boff     = bsum + 512;                           // 512
    float* colsum   = (float*)(boff + 512);                 // 512
    float* colsumsq = colsum + 512;                         // 512
    float* meanv    = colsumsq + 512;                       // 512
    float* rstdv    = meanv + 512;                          // 512
    int*   csr_src  = (int*)(rstdv + 512);                  // NE
    float* csr_w    = (float*)(csr_src + NE);               // NE
    float* aggX1    = csr_w + NE;                           // NN*128
    float* bufA     = aggX1 + (size_t)NN * FIN;             // NN*512
    float* bufB     = bufA + (size_t)NN * HIDD;             // NN*512
    float* bufH3    = aggX1;                                // reuse (NN*40)
    float* agg3     = aggX1 + (size_t)NN * NCLS;            // NN*40

    const int B = 256;
    const int NB = ceil_div_ll(NN, 256);  // 391

    // --- CSR build (shared by all layers) ---
    hipMemsetAsync(degi, 0, (size_t)NN * 4, stream);
    deg_int_kernel<<<ceil_div_ll(NE, B), B, 0, stream>>>(dst, degi);
    dinv_from_deg_kernel<<<NB, B, 0, stream>>>(degi, dinv);
    scan_block_kernel<<<NB, B, 0, stream>>>(degi, rowptr, bsum);
    scan_bsum_kernel<<<1, 512, 0, stream>>>(bsum, boff, NB);
    add_offsets_kernel<<<NB, B, 0, stream>>>(rowptr, boff, cursor);
    scatter_kernel<<<ceil_div_ll(NE, B), B, 0, stream>>>(src, dst, dinv, cursor, csr_src, csr_w);

    // --- layer 1: agg(x) -> GEMM(128x512) -> BN -> relu ---
    agg_csr128_kernel<<<ceil_div_ll(NN, 4), B, 0, stream>>>(x, rowptr, degi, dinv, csr_src, csr_w, aggX1);
    {
        dim3 grid(HIDD / 64, ceil_div_ll(NN, 64));
        gemm_kernel<<<grid, B, 0, stream>>>(aggX1, W1, bufA, NN, FIN, HIDD);
    }
    hipMemsetAsync(colsum, 0, 1024 * 4, stream);
    {
        dim3 grid(ceil_div_ll(NN, 128), 2);
        colstats_kernel<<<grid, B, 0, stream>>>(bufA, HIDD, 128, colsum, colsumsq);
    }
    finalize_stats_kernel<<<2, B, 0, stream>>>(colsum, colsumsq, meanv, rstdv, HIDD);
    bn_apply_kernel<true, HIDD><<<ceil_div_ll((long long)NN * HIDD / 4, B), B, 0, stream>>>(
        bufA, bufA, meanv, rstdv, g1, be1);  // bufA = x3

    // --- layer 2: agg(x3) -> GEMM(512x512) -> BN -> relu -> x6 (in d_out) ---
    agg_csr512_kernel<<<ceil_div_ll(NN, 4), B, 0, stream>>>(bufA, rowptr, degi, dinv, csr_src, csr_w, bufB);
    {
        dim3 grid(HIDD / 64, ceil_div_ll(NN, 64));
        gemm_kernel<<<grid, B, 0, stream>>>(bufB, W2, bufA, NN, HIDD, HIDD);
    }
    hipMemsetAsync(colsum, 0, 1024 * 4, stream);
    {
        dim3 grid(ceil_div_ll(NN, 128), 2);
        colstats_kernel<<<grid, B, 0, stream>>>(bufA, HIDD, 128, colsum, colsumsq);
    }
    finalize_stats_kernel<<<2, B, 0, stream>>>(colsum, colsumsq, meanv, rstdv, HIDD);
    bn_apply_kernel<true, HIDD><<<ceil_div_ll((long long)NN * HIDD / 4, B), B, 0, stream>>>(
        bufA, x6, meanv, rstdv, g2, be2);  // x6 written directly to d_out

    // --- layer 3: GEMM(512x40) -> agg -> BN (no relu) ---
    {
        dim3 grid(1, ceil_div_ll(NN, 64));
        gemm_kernel<<<grid, B, 0, stream>>>(x6, W3, bufH3, NN, HIDD, NCLS);
    }
    agg_csr40_kernel<<<ceil_div_ll(NN, 4), B, 0, stream>>>(bufH3, rowptr, degi, dinv, csr_src, csr_w, agg3);
    hipMemsetAsync(colsum, 0, 1024 * 4, stream);
    {
        dim3 grid(ceil_div_ll(NN, 128), 1);
        colstats_kernel<<<grid, B, 0, stream>>>(agg3, NCLS, 128, colsum, colsumsq);
    }
    finalize_stats_kernel<<<1, B, 0, stream>>>(colsum, colsumsq, meanv, rstdv, NCLS);
    bn_apply_kernel<false, NCLS><<<ceil_div_ll((long long)NN * NCLS / 4, B), B, 0, stream>>>(
        agg3, out, meanv, rstdv, g3, be3);
}

// Round 3
// 1122.950 us; speedup vs baseline: 7.8618x; 1.8933x over previous
//
#include <hip/hip_runtime.h>
#include <cstddef>
#include <cstdint>

// GCN1: 3x (GCNConv -> BatchNorm -> ReLU[1,2]) on N=100k, E=800k.
// Round 3: bf16 MFMA GEMMs (16x16x32, 128x128 tile, BK=64, global_load_lds w=16,
// T2 XOR-swizzle source+read), bf16 activations end-to-end (halves agg traffic),
// GEMM writes bf16 directly; BN stats/apply on bf16 in-place.

#define NN 100000
#define MPAD 100096   // 782 * 128
#define NE 800000
#define FIN 128
#define HIDD 512
#define NCLS 40
#define BN_EPS 1e-5f

typedef unsigned short ushort_t;
typedef __bf16 bf16x8_t __attribute__((ext_vector_type(8)));
typedef float f32x4_t __attribute__((ext_vector_type(4)));

static inline int ceil_div_ll(long long a, long long b) { return (int)((a + b - 1) / b); }

__device__ inline unsigned f2u(float f) { union { float f; unsigned u; } v; v.f = f; return v.u; }
__device__ inline float u2f(unsigned u) { union { unsigned u; float f; } v; v.u = u; return v.f; }
__device__ inline unsigned rne16(float f) {  // f32 -> bf16 bits (RNE)
    unsigned u = f2u(f);
    return (u + 0x7FFFu + ((u >> 16) & 1u)) >> 16;
}
__device__ inline unsigned pack2(float lo, float hi) { return rne16(lo) | (rne16(hi) << 16); }

__device__ inline void gld16(const void* g, void* l) {
    __builtin_amdgcn_global_load_lds(
        (const __attribute__((address_space(1))) unsigned int*)g,
        (__attribute__((address_space(3))) unsigned int*)l, 16, 0, 0);
}

// ---------------- CSR build ----------------
__global__ void deg_int_kernel(const int* __restrict__ dst, int* __restrict__ degi) {
    int e = blockIdx.x * 256 + threadIdx.x;
    if (e < NE) atomicAdd(&degi[dst[e]], 1);
}

__global__ void dinv_from_deg_kernel(const int* __restrict__ degi, float* __restrict__ dinv) {
    int i = blockIdx.x * 256 + threadIdx.x;
    if (i < NN) dinv[i] = rsqrtf((float)degi[i] + 1.0f);
}

__global__ void scan_block_kernel(const int* __restrict__ degi, int* __restrict__ rowptr,
                                  int* __restrict__ bsum) {
    __shared__ int tmp[256];
    int t = threadIdx.x;
    int i = blockIdx.x * 256 + t;
    int v = (i < NN) ? degi[i] : 0;
    tmp[t] = v;
    __syncthreads();
    #pragma unroll
    for (int off = 1; off < 256; off <<= 1) {
        int u = (t >= off) ? tmp[t - off] : 0;
        __syncthreads();
        tmp[t] += u;
        __syncthreads();
    }
    if (i < NN) rowptr[i] = tmp[t] - v;
    if (t == 255) bsum[blockIdx.x] = tmp[255];
}

__global__ void scan_bsum_kernel(const int* __restrict__ bsum, int* __restrict__ boff, int nb) {
    __shared__ int tmp[512];
    int t = threadIdx.x;
    int v = (t < nb) ? bsum[t] : 0;
    tmp[t] = v;
    __syncthreads();
    #pragma unroll
    for (int off = 1; off < 512; off <<= 1) {
        int u = (t >= off) ? tmp[t - off] : 0;
        __syncthreads();
        tmp[t] += u;
        __syncthreads();
    }
    if (t < nb) boff[t] = tmp[t] - v;
}

__global__ void add_offsets_kernel(int* __restrict__ rowptr, const int* __restrict__ boff,
                                   int* __restrict__ cursor) {
    int i = blockIdx.x * 256 + threadIdx.x;
    if (i < NN) {
        int r = rowptr[i] + boff[i >> 8];
        rowptr[i] = r;
        cursor[i] = r;
    }
}

__global__ void scatter_kernel(const int* __restrict__ src, const int* __restrict__ dst,
                               const float* __restrict__ dinv, int* __restrict__ cursor,
                               int* __restrict__ csr_src, float* __restrict__ csr_w) {
    int e = blockIdx.x * 256 + threadIdx.x;
    if (e >= NE) return;
    int s = src[e];
    int d = dst[e];
    int pos = atomicAdd(&cursor[d], 1);
    csr_src[pos] = s;
    csr_w[pos] = dinv[s];
}

// ---------------- conversions ----------------
// fp32 [rows][8k] -> bf16, vectorized 8/thread
__global__ void f32_to_bf16_kernel(const float* __restrict__ X, unsigned* __restrict__ Y,
                                   long long n8) {
    long long i = (long long)blockIdx.x * 256 + threadIdx.x;
    if (i >= n8) return;
    const float4* X4 = reinterpret_cast<const float4*>(X);
    float4 a = X4[i * 2], b = X4[i * 2 + 1];
    uint4 o;
    o.x = pack2(a.x, a.y); o.y = pack2(a.z, a.w);
    o.z = pack2(b.x, b.y); o.w = pack2(b.z, b.w);
    reinterpret_cast<uint4*>(Y)[i] = o;
}

// W [K][Nw] fp32 -> Wt [Npad][K] bf16 (rows >= Nw zeroed)
__global__ void transpose_w_kernel(const float* __restrict__ W, ushort_t* __restrict__ Wt,
                                   int K, int Nw, int Npad) {
    int gid = blockIdx.x * 256 + threadIdx.x;
    if (gid >= Npad * K) return;
    int k = gid % K;
    int n = gid / K;
    float v = (n < Nw) ? W[(size_t)k * Nw + n] : 0.0f;
    Wt[gid] = (ushort_t)rne16(v);
}

// ---------------- CSR aggregation (bf16 rows) ----------------
// out[d] = dinv[d]*sum_e(dinv[src]*h[src]) + dinv[d]^2*h[d]
__global__ __launch_bounds__(256) void agg_csr512b_kernel(
        const ushort_t* __restrict__ h, const int* __restrict__ rowptr,
        const int* __restrict__ degi, const float* __restrict__ dinv,
        const int* __restrict__ csr_src, const float* __restrict__ csr_w,
        ushort_t* __restrict__ out) {
    int wid = (blockIdx.x * 256 + threadIdx.x) >> 6;
    int lane = threadIdx.x & 63;
    if (wid >= NN) return;
    int r0 = rowptr[wid];
    int n = degi[wid];
    float di = dinv[wid];
    float a[8] = {0.f, 0.f, 0.f, 0.f, 0.f, 0.f, 0.f, 0.f};
    for (int j = 0; j < n; ++j) {
        int s = csr_src[r0 + j];
        float w = csr_w[r0 + j];
        uint4 v = reinterpret_cast<const uint4*>(h + (size_t)s * HIDD)[lane];
        a[0] += w * u2f(v.x << 16); a[1] += w * u2f(v.x & 0xFFFF0000u);
        a[2] += w * u2f(v.y << 16); a[3] += w * u2f(v.y & 0xFFFF0000u);
        a[4] += w * u2f(v.z << 16); a[5] += w * u2f(v.z & 0xFFFF0000u);
        a[6] += w * u2f(v.w << 16); a[7] += w * u2f(v.w & 0xFFFF0000u);
    }
    uint4 sv = reinterpret_cast<const uint4*>(h + (size_t)wid * HIDD)[lane];
    float sq = di * di;
    float o[8];
    o[0] = di * a[0] + sq * u2f(sv.x << 16); o[1] = di * a[1] + sq * u2f(sv.x & 0xFFFF0000u);
    o[2] = di * a[2] + sq * u2f(sv.y << 16); o[3] = di * a[3] + sq * u2f(sv.y & 0xFFFF0000u);
    o[4] = di * a[4] + sq * u2f(sv.z << 16); o[5] = di * a[5] + sq * u2f(sv.z & 0xFFFF0000u);
    o[6] = di * a[6] + sq * u2f(sv.w << 16); o[7] = di * a[7] + sq * u2f(sv.w & 0xFFFF0000u);
    uint4 ov;
    ov.x = pack2(o[0], o[1]); ov.y = pack2(o[2], o[3]);
    ov.z = pack2(o[4], o[5]); ov.w = pack2(o[6], o[7]);
    reinterpret_cast<uint4*>(out + (size_t)wid * HIDD)[lane] = ov;
}

__global__ __launch_bounds__(256) void agg_csr128b_kernel(
        const ushort_t* __restrict__ h, const int* __restrict__ rowptr,
        const int* __restrict__ degi, const float* __restrict__ dinv,
        const int* __restrict__ csr_src, const float* __restrict__ csr_w,
        ushort_t* __restrict__ out) {
    int wid = (blockIdx.x * 256 + threadIdx.x) >> 6;
    int lane = threadIdx.x & 63;
    if (wid >= NN) return;
    int r0 = rowptr[wid];
    int n = degi[wid];
    float di = dinv[wid];
    float a0 = 0.f, a1 = 0.f;
    for (int j = 0; j < n; ++j) {
        int s = csr_src[r0 + j];
        float w = csr_w[r0 + j];
        unsigned v = reinterpret_cast<const unsigned*>(h + (size_t)s * FIN)[lane];
        a0 += w * u2f(v << 16);
        a1 += w * u2f(v & 0xFFFF0000u);
    }
    unsigned sv = reinterpret_cast<const unsigned*>(h + (size_t)wid * FIN)[lane];
    float sq = di * di;
    float o0 = di * a0 + sq * u2f(sv << 16);
    float o1 = di * a1 + sq * u2f(sv & 0xFFFF0000u);
    reinterpret_cast<unsigned*>(out + (size_t)wid * FIN)[lane] = pack2(o0, o1);
}

__global__ __launch_bounds__(256) void agg_csr40_kernel(
        const float* __restrict__ h, const int* __restrict__ rowptr,
        const int* __restrict__ degi, const float* __restrict__ dinv,
        const int* __restrict__ csr_src, const float* __restrict__ csr_w,
        float* __restrict__ out) {
    int wid = (blockIdx.x * 256 + threadIdx.x) >> 6;
    int lane = threadIdx.x & 63;
    if (wid >= NN) return;
    int r0 = rowptr[wid];
    int n = degi[wid];
    float di = dinv[wid];
    if (lane < 10) {
        float4 a = make_float4(0.f, 0.f, 0.f, 0.f);
        for (int j = 0; j < n; ++j) {
            int s = csr_src[r0 + j];
            float w = csr_w[r0 + j];
            float4 v = reinterpret_cast<const float4*>(h + (size_t)s * NCLS)[lane];
            a.x += w * v.x; a.y += w * v.y; a.z += w * v.z; a.w += w * v.w;
        }
        float4 sv = reinterpret_cast<const float4*>(h + (size_t)wid * NCLS)[lane];
        float sq = di * di;
        float4 o;
        o.x = di * a.x + sq * sv.x; o.y = di * a.y + sq * sv.y;
        o.z = di * a.z + sq * sv.z; o.w = di * a.w + sq * sv.w;
        reinterpret_cast<float4*>(out + (size_t)wid * NCLS)[lane] = o;
    }
}

// ---------------- bf16 MFMA GEMM ----------------
// C[M,N(mask)] = A[Mpad,K]bf16 @ Bt[Npad,K]bf16^T ; BM=128, BK=64.
// LDS: row-major [rows][64] bf16 (128B/row, 8x16B chunks), chunk XOR (row&7) swizzle,
// staged via global_load_lds(16B) with inverse-swizzled global source (rule #21).
template<int WM, int WN, int BNt, bool OUTBF>
__global__ __launch_bounds__(256) void gemm_bf16_kernel(
        const ushort_t* __restrict__ A, const ushort_t* __restrict__ Bt,
        void* __restrict__ C, int M, int N, int K, int ldc) {
    constexpr int BM = 128;
    constexpr int SM = BM / WM;
    constexpr int SN = BNt / WN;
    constexpr int MFR = SM / 16;
    constexpr int NFR = SN / 16;
    constexpr int AR = (BM * 128) / 4096;   // staging rounds (256 thr x 16B = 4KB)
    constexpr int BR = (BNt * 128) / 4096;

    __shared__ __align__(16) char smem[(BM + BNt) * 128];
    char* Asm = smem;
    char* Bsm = smem + BM * 128;

    const int tid = threadIdx.x;
    const int l = tid & 63;
    const int w = tid >> 6;
    const int wm = w / WN, wn = w % WN;
    const int m0 = blockIdx.y * BM;
    const int n0 = blockIdx.x * BNt;

    f32x4_t acc[MFR][NFR];
    #pragma unroll
    for (int mi = 0; mi < MFR; ++mi)
        #pragma unroll
        for (int ni = 0; ni < NFR; ++ni)
            acc[mi][ni] = (f32x4_t){0.f, 0.f, 0.f, 0.f};

    const int lrow = l >> 3;     // 0..7, row within wave's 8-row staging slab
    const int pchunk = l & 7;    // physical 16B chunk

    for (int k0 = 0; k0 < K; k0 += 64) {
        #pragma unroll
        for (int g = 0; g < AR; ++g) {
            int lr = g * 32 + w * 8 + lrow;
            int lchunk = pchunk ^ (lr & 7);
            gld16((const char*)A + ((size_t)(m0 + lr) * K + k0 + lchunk * 8) * 2,
                  Asm + (g * 32 + w * 8) * 128);
        }
        #pragma unroll
        for (int g = 0; g < BR; ++g) {
            int lr = g * 32 + w * 8 + lrow;
            int lchunk = pchunk ^ (lr & 7);
            gld16((const char*)Bt + ((size_t)(n0 + lr) * K + k0 + lchunk * 8) * 2,
                  Bsm + (g * 32 + w * 8) * 128);
        }
        __syncthreads();  // drains vmcnt(0)

        #pragma unroll
        for (int kk = 0; kk < 2; ++kk) {
            bf16x8_t af[MFR], bfr[NFR];
            #pragma unroll
            for (int mi = 0; mi < MFR; ++mi) {
                int ar = wm * SM + mi * 16 + (l & 15);
                int lchunk = (kk * 4 + (l >> 4)) ^ (ar & 7);
                af[mi] = *reinterpret_cast<const bf16x8_t*>(Asm + ar * 128 + lchunk * 16);
            }
            #pragma unroll
            for (int ni = 0; ni < NFR; ++ni) {
                int br = wn * SN + ni * 16 + (l & 15);
                int lchunk = (kk * 4 + (l >> 4)) ^ (br & 7);
                bfr[ni] = *reinterpret_cast<const bf16x8_t*>(Bsm + br * 128 + lchunk * 16);
            }
            #pragma unroll
            for (int mi = 0; mi < MFR; ++mi)
                #pragma unroll
                for (int ni = 0; ni < NFR; ++ni)
                    acc[mi][ni] = __builtin_amdgcn_mfma_f32_16x16x32_bf16(
                        af[mi], bfr[ni], acc[mi][ni], 0, 0, 0);
        }
        __syncthreads();
    }

    // epilogue: D row=(lane>>4)*4+reg, col=lane&15 (m89-verified layout)
    #pragma unroll
    for (int mi = 0; mi < MFR; ++mi) {
        #pragma unroll
        for (int r = 0; r < 4; ++r) {
            int row = m0 + wm * SM + mi * 16 + (l >> 4) * 4 + r;
            if (row >= M) continue;
            #pragma unroll
            for (int ni = 0; ni < NFR; ++ni) {
                int col = n0 + wn * SN + ni * 16 + (l & 15);
                if (col < N) {
                    float v = acc[mi][ni][r];
                    if (OUTBF)
                        ((ushort_t*)C)[(size_t)row * ldc + col] = (ushort_t)rne16(v);
                    else
                        ((float*)C)[(size_t)row * ldc + col] = v;
                }
            }
        }
    }
}

// ---------------- BatchNorm ----------------
__global__ void colstats_bf16_kernel(const ushort_t* __restrict__ X, int C, int rows_per_block,
                                     float* __restrict__ colsum, float* __restrict__ colsumsq) {
    int col = blockIdx.y * 256 + threadIdx.x;
    if (col >= C) return;
    int r0 = blockIdx.x * rows_per_block;
    int r1 = min(r0 + rows_per_block, NN);
    float s = 0.f, ss = 0.f;
    for (int r = r0; r < r1; ++r) {
        float v = u2f(((unsigned)X[(size_t)r * C + col]) << 16);
        s += v;
        ss += v * v;
    }
    atomicAdd(&colsum[col], s);
    atomicAdd(&colsumsq[col], ss);
}

__global__ void colstats_f32_kernel(const float* __restrict__ X, int C, int rows_per_block,
                                    float* __restrict__ colsum, float* __restrict__ colsumsq) {
    int col = blockIdx.y * 256 + threadIdx.x;
    if (col >= C) return;
    int r0 = blockIdx.x * rows_per_block;
    int r1 = min(r0 + rows_per_block, NN);
    float s = 0.f, ss = 0.f;
    for (int r = r0; r < r1; ++r) {
        float v = X[(size_t)r * C + col];
        s += v;
        ss += v * v;
    }
    atomicAdd(&colsum[col], s);
    atomicAdd(&colsumsq[col], ss);
}

__global__ void finalize_stats_kernel(const float* __restrict__ colsum,
                                      const float* __restrict__ colsumsq,
                                      float* __restrict__ meanv, float* __restrict__ rstdv,
                                      int C) {
    int c = blockIdx.x * 256 + threadIdx.x;
    if (c >= C) return;
    float mu = colsum[c] * (1.0f / NN);
    float var = colsumsq[c] * (1.0f / NN) - mu * mu;
    meanv[c] = mu;
    rstdv[c] = rsqrtf(var + BN_EPS);
}

// in-place BN(+ReLU) on bf16 [NN][C]; optionally also write fp32 copy (layer-2 -> x6)
template<bool RELU>
__global__ void bn_bf16_kernel(ushort_t* __restrict__ Y, float* __restrict__ f32out,
                               const float* __restrict__ meanv, const float* __restrict__ rstdv,
                               const float* __restrict__ g, const float* __restrict__ be, int C) {
    long long i = (long long)blockIdx.x * 256 + threadIdx.x;
    long long tot = (long long)NN * (C / 8);
    if (i >= tot) return;
    int c0 = (int)(i % (C / 8)) * 8;
    uint4 v = reinterpret_cast<const uint4*>(Y)[i];
    float f[8];
    f[0] = u2f(v.x << 16); f[1] = u2f(v.x & 0xFFFF0000u);
    f[2] = u2f(v.y << 16); f[3] = u2f(v.y & 0xFFFF0000u);
    f[4] = u2f(v.z << 16); f[5] = u2f(v.z & 0xFFFF0000u);
    f[6] = u2f(v.w << 16); f[7] = u2f(v.w & 0xFFFF0000u);
    #pragma unroll
    for (int j = 0; j < 8; ++j) {
        float y = g[c0 + j] * (f[j] - meanv[c0 + j]) * rstdv[c0 + j] + be[c0 + j];
        if (RELU) y = fmaxf(y, 0.f);
        f[j] = y;
    }
    uint4 o;
    o.x = pack2(f[0], f[1]); o.y = pack2(f[2], f[3]);
    o.z = pack2(f[4], f[5]); o.w = pack2(f[6], f[7]);
    reinterpret_cast<uint4*>(Y)[i] = o;
    if (f32out) {
        long long row = i / (C / 8);
        float* p = f32out + row * C + c0;
        reinterpret_cast<float4*>(p)[0] = make_float4(f[0], f[1], f[2], f[3]);
        reinterpret_cast<float4*>(p)[1] = make_float4(f[4], f[5], f[6], f[7]);
    }
}

template<bool RELU, int C>
__global__ void bn_f32_kernel(const float* __restrict__ X, float* __restrict__ Y,
                              const float* __restrict__ meanv, const float* __restrict__ rstdv,
                              const float* __restrict__ g, const float* __restrict__ be) {
    const long long TOT = (long long)NN * (C / 4);
    long long i = (long long)blockIdx.x * 256 + threadIdx.x;
    if (i >= TOT) return;
    int c = (int)((i % (C / 4)) * 4);
    float4 v = reinterpret_cast<const float4*>(X)[i];
    float r[4] = {v.x, v.y, v.z, v.w};
    #pragma unroll
    for (int j = 0; j < 4; ++j) {
        float y = g[c + j] * (r[j] - meanv[c + j]) * rstdv[c + j] + be[c + j];
        if (RELU) y = fmaxf(y, 0.f);
        r[j] = y;
    }
    reinterpret_cast<float4*>(Y)[i] = make_float4(r[0], r[1], r[2], r[3]);
}

// ---------------- orchestration ----------------
extern "C" void kernel_launch(void* const* d_in, const int* in_sizes, int n_in,
                              void* d_out, int out_size, void* d_ws, size_t ws_size,
                              hipStream_t stream) {
    const float* x   = (const float*)d_in[0];
    const int*   ei  = (const int*)d_in[1];
    const float* W1  = (const float*)d_in[2];
    const float* g1  = (const float*)d_in[4];
    const float* be1 = (const float*)d_in[5];
    const float* W2  = (const float*)d_in[6];
    const float* g2  = (const float*)d_in[8];
    const float* be2 = (const float*)d_in[9];
    const float* W3  = (const float*)d_in[10];
    const float* g3  = (const float*)d_in[12];
    const float* be3 = (const float*)d_in[13];

    const int* src = ei;
    const int* dst = ei + NE;

    float* out = (float*)d_out;                 // [NN, 40]
    float* x6  = out + (size_t)NN * NCLS;       // [NN, 512] fp32 second output

    // byte-offset workspace layout (256B aligned blocks)
    char* wp = (char*)d_ws;
    size_t o = 0;
    auto take = [&](size_t bytes) { char* p = wp + o; o = (o + bytes + 255) & ~(size_t)255; return p; };
    float*    dinv     = (float*)take((size_t)NN * 4);
    int*      degi     = (int*)take((size_t)NN * 4);
    int*      rowptr   = (int*)take((size_t)NN * 4);
    int*      cursor   = (int*)take((size_t)NN * 4);
    int*      bsum     = (int*)take(512 * 4);
    int*      boff     = (int*)take(512 * 4);
    float*    colsum   = (float*)take(512 * 4);
    float*    colsumsq = (float*)take(512 * 4);
    float*    meanv    = (float*)take(512 * 4);
    float*    rstdv    = (float*)take(512 * 4);
    int*      csr_src  = (int*)take((size_t)NE * 4);
    float*    csr_w    = (float*)take((size_t)NE * 4);
    ushort_t* W1t      = (ushort_t*)take((size_t)512 * 128 * 2);
    ushort_t* W2t      = (ushort_t*)take((size_t)512 * 512 * 2);
    ushort_t* W3t      = (ushort_t*)take((size_t)64 * 512 * 2);
    ushort_t* xb       = (ushort_t*)take((size_t)NN * FIN * 2);     // x in bf16
    ushort_t* aggX1b   = (ushort_t*)take((size_t)MPAD * FIN * 2);   // agg(x) bf16
    ushort_t* y1b      = (ushort_t*)take((size_t)MPAD * HIDD * 2);  // gemm1 out -> x3b (in-place BN)
    ushort_t* aggX3b   = (ushort_t*)take((size_t)MPAD * HIDD * 2);  // agg(x3) bf16
    ushort_t* y2b      = (ushort_t*)take((size_t)MPAD * HIDD * 2);  // gemm2 out -> x6b (in-place BN)
    float*    h3       = (float*)take((size_t)NN * NCLS * 4);       // gemm3 out fp32
    float*    agg3     = (float*)take((size_t)NN * NCLS * 4);

    const int B = 256;
    const int NB = ceil_div_ll(NN, 256);

    // --- CSR build ---
    hipMemsetAsync(degi, 0, (size_t)NN * 4, stream);
    deg_int_kernel<<<ceil_div_ll(NE, B), B, 0, stream>>>(dst, degi);
    dinv_from_deg_kernel<<<NB, B, 0, stream>>>(degi, dinv);
    scan_block_kernel<<<NB, B, 0, stream>>>(degi, rowptr, bsum);
    scan_bsum_kernel<<<1, 512, 0, stream>>>(bsum, boff, NB);
    add_offsets_kernel<<<NB, B, 0, stream>>>(rowptr, boff, cursor);
    scatter_kernel<<<ceil_div_ll(NE, B), B, 0, stream>>>(src, dst, dinv, cursor, csr_src, csr_w);

    // --- weight prep (bf16 transposed) + x -> bf16 ---
    transpose_w_kernel<<<ceil_div_ll(512 * 128, B), B, 0, stream>>>(W1, W1t, 128, 512, 512);
    transpose_w_kernel<<<ceil_div_ll(512 * 512, B), B, 0, stream>>>(W2, W2t, 512, 512, 512);
    transpose_w_kernel<<<ceil_div_ll(64 * 512, B), B, 0, stream>>>(W3, W3t, 512, 40, 64);
    f32_to_bf16_kernel<<<ceil_div_ll((long long)NN * FIN / 8, B), B, 0, stream>>>(
        x, (unsigned*)xb, (long long)NN * FIN / 8);

    const int MG = MPAD / 128;  // 782

    // --- layer 1: agg(xb) -> MFMA GEMM(K=128) -> BN+ReLU (in-place bf16) ---
    agg_csr128b_kernel<<<ceil_div_ll(NN, 4), B, 0, stream>>>(xb, rowptr, degi, dinv, csr_src, csr_w, aggX1b);
    {
        dim3 grid(HIDD / 128, MG);
        gemm_bf16_kernel<2, 2, 128, true><<<grid, B, 0, stream>>>(aggX1b, W1t, y1b, NN, HIDD, FIN, HIDD);
    }
    hipMemsetAsync(colsum, 0, 4096, stream);
    {
        dim3 grid(ceil_div_ll(NN, 128), 2);
        colstats_bf16_kernel<<<grid, B, 0, stream>>>(y1b, HIDD, 128, colsum, colsumsq);
    }
    finalize_stats_kernel<<<2, B, 0, stream>>>(colsum, colsumsq, meanv, rstdv, HIDD);
    bn_bf16_kernel<true><<<ceil_div_ll((long long)NN * HIDD / 8, B), B, 0, stream>>>(
        y1b, nullptr, meanv, rstdv, g1, be1, HIDD);  // y1b = x3 bf16

    // --- layer 2: agg(x3) -> MFMA GEMM(K=512) -> BN+ReLU -> x6 fp32 + x6b bf16 ---
    agg_csr512b_kernel<<<ceil_div_ll(NN, 4), B, 0, stream>>>(y1b, rowptr, degi, dinv, csr_src, csr_w, aggX3b);
    {
        dim3 grid(HIDD / 128, MG);
        gemm_bf16_kernel<2, 2, 128, true><<<grid, B, 0, stream>>>(aggX3b, W2t, y2b, NN, HIDD, HIDD, HIDD);
    }
    hipMemsetAsync(colsum, 0, 4096, stream);
    {
        dim3 grid(ceil_div_ll(NN, 128), 2);
        colstats_bf16_kernel<<<grid, B, 0, stream>>>(y2b, HIDD, 128, colsum, colsumsq);
    }
    finalize_stats_kernel<<<2, B, 0, stream>>>(colsum, colsumsq, meanv, rstdv, HIDD);
    bn_bf16_kernel<true><<<ceil_div_ll((long long)NN * HIDD / 8, B), B, 0, stream>>>(
        y2b, x6, meanv, rstdv, g2, be2, HIDD);  // y2b = x6 bf16; x6 fp32 -> d_out

    // --- layer 3: MFMA GEMM(N=40) -> agg -> BN ---
    {
        dim3 grid(1, MG);
        gemm_bf16_kernel<4, 1, 64, false><<<grid, B, 0, stream>>>(y2b, W3t, h3, NN, NCLS, HIDD, NCLS);
    }
    agg_csr40_kernel<<<ceil_div_ll(NN, 4), B, 0, stream>>>(h3, rowptr, degi, dinv, csr_src, csr_w, agg3);
    hipMemsetAsync(colsum, 0, 4096, stream);
    {
        dim3 grid(ceil_div_ll(NN, 128), 1);
        colstats_f32_kernel<<<grid, B, 0, stream>>>(agg3, NCLS, 128, colsum, colsumsq);
    }
    finalize_stats_kernel<<<1, B, 0, stream>>>(colsum, colsumsq, meanv, rstdv, NCLS);
    bn_f32_kernel<false, NCLS><<<ceil_div_ll((long long)NN * NCLS / 4, B), B, 0, stream>>>(
        agg3, out, meanv, rstdv, g3, be3);
}

// Round 4
// 985.135 us; speedup vs baseline: 8.9616x; 1.1399x over previous
//
#include <hip/hip_runtime.h>
#include <cstddef>
#include <cstdint>

// GCN1: 3x (GCNConv -> BatchNorm -> ReLU[1,2]) on N=100k, E=800k.
// Round 4: pass-fusion round.
//  - BN column stats fused into GEMM epilogue (shuffle-reduce + LDS + global atomics)
//  - layer-1 BN+ReLU apply fused into layer-2 gather (per-lane channel affine)
//  - gather loops unrolled x2 for memory-level parallelism
//  - bf16 MFMA GEMM (16x16x32, 128-row tile, BK=64, global_load_lds w=16, T2 swizzle)

#define NN 100000
#define MPAD 100096   // 782 * 128
#define NE 800000
#define FIN 128
#define HIDD 512
#define NCLS 40
#define BN_EPS 1e-5f

typedef unsigned short ushort_t;
typedef __bf16 bf16x8_t __attribute__((ext_vector_type(8)));
typedef float f32x4_t __attribute__((ext_vector_type(4)));

static inline int ceil_div_ll(long long a, long long b) { return (int)((a + b - 1) / b); }

__device__ inline unsigned f2u(float f) { union { float f; unsigned u; } v; v.f = f; return v.u; }
__device__ inline float u2f(unsigned u) { union { unsigned u; float f; } v; v.u = u; return v.f; }
__device__ inline unsigned rne16(float f) {  // f32 -> bf16 bits (RNE)
    unsigned u = f2u(f);
    return (u + 0x7FFFu + ((u >> 16) & 1u)) >> 16;
}
__device__ inline unsigned pack2(float lo, float hi) { return rne16(lo) | (rne16(hi) << 16); }

__device__ inline void gld16(const void* g, void* l) {
    __builtin_amdgcn_global_load_lds(
        (const __attribute__((address_space(1))) unsigned int*)g,
        (__attribute__((address_space(3))) unsigned int*)l, 16, 0, 0);
}

// ---------------- CSR build ----------------
__global__ void deg_int_kernel(const int* __restrict__ dst, int* __restrict__ degi) {
    int e = blockIdx.x * 256 + threadIdx.x;
    if (e < NE) atomicAdd(&degi[dst[e]], 1);
}

__global__ void dinv_from_deg_kernel(const int* __restrict__ degi, float* __restrict__ dinv) {
    int i = blockIdx.x * 256 + threadIdx.x;
    if (i < NN) dinv[i] = rsqrtf((float)degi[i] + 1.0f);
}

__global__ void scan_block_kernel(const int* __restrict__ degi, int* __restrict__ rowptr,
                                  int* __restrict__ bsum) {
    __shared__ int tmp[256];
    int t = threadIdx.x;
    int i = blockIdx.x * 256 + t;
    int v = (i < NN) ? degi[i] : 0;
    tmp[t] = v;
    __syncthreads();
    #pragma unroll
    for (int off = 1; off < 256; off <<= 1) {
        int u = (t >= off) ? tmp[t - off] : 0;
        __syncthreads();
        tmp[t] += u;
        __syncthreads();
    }
    if (i < NN) rowptr[i] = tmp[t] - v;
    if (t == 255) bsum[blockIdx.x] = tmp[255];
}

__global__ void scan_bsum_kernel(const int* __restrict__ bsum, int* __restrict__ boff, int nb) {
    __shared__ int tmp[512];
    int t = threadIdx.x;
    int v = (t < nb) ? bsum[t] : 0;
    tmp[t] = v;
    __syncthreads();
    #pragma unroll
    for (int off = 1; off < 512; off <<= 1) {
        int u = (t >= off) ? tmp[t - off] : 0;
        __syncthreads();
        tmp[t] += u;
        __syncthreads();
    }
    if (t < nb) boff[t] = tmp[t] - v;
}

__global__ void add_offsets_kernel(int* __restrict__ rowptr, const int* __restrict__ boff,
                                   int* __restrict__ cursor) {
    int i = blockIdx.x * 256 + threadIdx.x;
    if (i < NN) {
        int r = rowptr[i] + boff[i >> 8];
        rowptr[i] = r;
        cursor[i] = r;
    }
}

__global__ void scatter_kernel(const int* __restrict__ src, const int* __restrict__ dst,
                               const float* __restrict__ dinv, int* __restrict__ cursor,
                               int* __restrict__ csr_src, float* __restrict__ csr_w) {
    int e = blockIdx.x * 256 + threadIdx.x;
    if (e >= NE) return;
    int s = src[e];
    int d = dst[e];
    int pos = atomicAdd(&cursor[d], 1);
    csr_src[pos] = s;
    csr_w[pos] = dinv[s];
}

// ---------------- conversions ----------------
__global__ void f32_to_bf16_kernel(const float* __restrict__ X, unsigned* __restrict__ Y,
                                   long long n8) {
    long long i = (long long)blockIdx.x * 256 + threadIdx.x;
    if (i >= n8) return;
    const float4* X4 = reinterpret_cast<const float4*>(X);
    float4 a = X4[i * 2], b = X4[i * 2 + 1];
    uint4 o;
    o.x = pack2(a.x, a.y); o.y = pack2(a.z, a.w);
    o.z = pack2(b.x, b.y); o.w = pack2(b.z, b.w);
    reinterpret_cast<uint4*>(Y)[i] = o;
}

// W [K][Nw] fp32 -> Wt [Npad][K] bf16 (rows >= Nw zeroed)
__global__ void transpose_w_kernel(const float* __restrict__ W, ushort_t* __restrict__ Wt,
                                   int K, int Nw, int Npad) {
    int gid = blockIdx.x * 256 + threadIdx.x;
    if (gid >= Npad * K) return;
    int k = gid % K;
    int n = gid / K;
    float v = (n < Nw) ? W[(size_t)k * Nw + n] : 0.0f;
    Wt[gid] = (ushort_t)rne16(v);
}

// ---------------- CSR aggregation ----------------
// layer-2 gather with layer-1 BN+ReLU fused into the read:
// x3[s][c] = relu(sc[c]*y1[s][c] + sh[c]);  out[d] = di*sum(w*x3[s]) + di^2*x3[d]
__global__ __launch_bounds__(256) void agg_bn512_kernel(
        const ushort_t* __restrict__ h, const int* __restrict__ rowptr,
        const int* __restrict__ degi, const float* __restrict__ dinv,
        const int* __restrict__ csr_src, const float* __restrict__ csr_w,
        const float* __restrict__ meanv, const float* __restrict__ rstdv,
        const float* __restrict__ g, const float* __restrict__ be,
        ushort_t* __restrict__ out) {
    int wid = (blockIdx.x * 256 + threadIdx.x) >> 6;
    int lane = threadIdx.x & 63;
    if (wid >= NN) return;
    const int c0 = lane * 8;
    float sc[8], sh[8];
    #pragma unroll
    for (int j = 0; j < 8; ++j) {
        float s = g[c0 + j] * rstdv[c0 + j];
        sc[j] = s;
        sh[j] = be[c0 + j] - meanv[c0 + j] * s;
    }
    int r0 = rowptr[wid];
    int n = degi[wid];
    float di = dinv[wid];
    float a[8] = {0.f, 0.f, 0.f, 0.f, 0.f, 0.f, 0.f, 0.f};

    auto accum = [&](uint4 v, float w) {
        float f[8];
        f[0] = u2f(v.x << 16); f[1] = u2f(v.x & 0xFFFF0000u);
        f[2] = u2f(v.y << 16); f[3] = u2f(v.y & 0xFFFF0000u);
        f[4] = u2f(v.z << 16); f[5] = u2f(v.z & 0xFFFF0000u);
        f[6] = u2f(v.w << 16); f[7] = u2f(v.w & 0xFFFF0000u);
        #pragma unroll
        for (int j = 0; j < 8; ++j)
            a[j] += w * fmaxf(sc[j] * f[j] + sh[j], 0.f);
    };

    int j = 0;
    for (; j + 2 <= n; j += 2) {
        int s0 = csr_src[r0 + j], s1 = csr_src[r0 + j + 1];
        float w0 = csr_w[r0 + j], w1 = csr_w[r0 + j + 1];
        uint4 v0 = reinterpret_cast<const uint4*>(h + (size_t)s0 * HIDD)[lane];
        uint4 v1 = reinterpret_cast<const uint4*>(h + (size_t)s1 * HIDD)[lane];
        accum(v0, w0);
        accum(v1, w1);
    }
    if (j < n) {
        int s0 = csr_src[r0 + j];
        float w0 = csr_w[r0 + j];
        uint4 v0 = reinterpret_cast<const uint4*>(h + (size_t)s0 * HIDD)[lane];
        accum(v0, w0);
    }

    uint4 sv = reinterpret_cast<const uint4*>(h + (size_t)wid * HIDD)[lane];
    float fs[8];
    fs[0] = u2f(sv.x << 16); fs[1] = u2f(sv.x & 0xFFFF0000u);
    fs[2] = u2f(sv.y << 16); fs[3] = u2f(sv.y & 0xFFFF0000u);
    fs[4] = u2f(sv.z << 16); fs[5] = u2f(sv.z & 0xFFFF0000u);
    fs[6] = u2f(sv.w << 16); fs[7] = u2f(sv.w & 0xFFFF0000u);
    float sq = di * di;
    float o[8];
    #pragma unroll
    for (int jj = 0; jj < 8; ++jj)
        o[jj] = di * a[jj] + sq * fmaxf(sc[jj] * fs[jj] + sh[jj], 0.f);
    uint4 ov;
    ov.x = pack2(o[0], o[1]); ov.y = pack2(o[2], o[3]);
    ov.z = pack2(o[4], o[5]); ov.w = pack2(o[6], o[7]);
    reinterpret_cast<uint4*>(out + (size_t)wid * HIDD)[lane] = ov;
}

__global__ __launch_bounds__(256) void agg_csr128b_kernel(
        const ushort_t* __restrict__ h, const int* __restrict__ rowptr,
        const int* __restrict__ degi, const float* __restrict__ dinv,
        const int* __restrict__ csr_src, const float* __restrict__ csr_w,
        ushort_t* __restrict__ out) {
    int wid = (blockIdx.x * 256 + threadIdx.x) >> 6;
    int lane = threadIdx.x & 63;
    if (wid >= NN) return;
    int r0 = rowptr[wid];
    int n = degi[wid];
    float di = dinv[wid];
    float a0 = 0.f, a1 = 0.f;
    int j = 0;
    for (; j + 2 <= n; j += 2) {
        int s0 = csr_src[r0 + j], s1 = csr_src[r0 + j + 1];
        float w0 = csr_w[r0 + j], w1 = csr_w[r0 + j + 1];
        unsigned v0 = reinterpret_cast<const unsigned*>(h + (size_t)s0 * FIN)[lane];
        unsigned v1 = reinterpret_cast<const unsigned*>(h + (size_t)s1 * FIN)[lane];
        a0 += w0 * u2f(v0 << 16) + w1 * u2f(v1 << 16);
        a1 += w0 * u2f(v0 & 0xFFFF0000u) + w1 * u2f(v1 & 0xFFFF0000u);
    }
    if (j < n) {
        int s0 = csr_src[r0 + j];
        float w0 = csr_w[r0 + j];
        unsigned v0 = reinterpret_cast<const unsigned*>(h + (size_t)s0 * FIN)[lane];
        a0 += w0 * u2f(v0 << 16);
        a1 += w0 * u2f(v0 & 0xFFFF0000u);
    }
    unsigned sv = reinterpret_cast<const unsigned*>(h + (size_t)wid * FIN)[lane];
    float sq = di * di;
    float o0 = di * a0 + sq * u2f(sv << 16);
    float o1 = di * a1 + sq * u2f(sv & 0xFFFF0000u);
    reinterpret_cast<unsigned*>(out + (size_t)wid * FIN)[lane] = pack2(o0, o1);
}

__global__ __launch_bounds__(256) void agg_csr40_kernel(
        const float* __restrict__ h, const int* __restrict__ rowptr,
        const int* __restrict__ degi, const float* __restrict__ dinv,
        const int* __restrict__ csr_src, const float* __restrict__ csr_w,
        float* __restrict__ out) {
    int wid = (blockIdx.x * 256 + threadIdx.x) >> 6;
    int lane = threadIdx.x & 63;
    if (wid >= NN) return;
    int r0 = rowptr[wid];
    int n = degi[wid];
    float di = dinv[wid];
    if (lane < 10) {
        float4 a = make_float4(0.f, 0.f, 0.f, 0.f);
        for (int j = 0; j < n; ++j) {
            int s = csr_src[r0 + j];
            float w = csr_w[r0 + j];
            float4 v = reinterpret_cast<const float4*>(h + (size_t)s * NCLS)[lane];
            a.x += w * v.x; a.y += w * v.y; a.z += w * v.z; a.w += w * v.w;
        }
        float4 sv = reinterpret_cast<const float4*>(h + (size_t)wid * NCLS)[lane];
        float sq = di * di;
        float4 o;
        o.x = di * a.x + sq * sv.x; o.y = di * a.y + sq * sv.y;
        o.z = di * a.z + sq * sv.z; o.w = di * a.w + sq * sv.w;
        reinterpret_cast<float4*>(out + (size_t)wid * NCLS)[lane] = o;
    }
}

// ---------------- bf16 MFMA GEMM (+ optional fused BN column stats) ----------------
// C[M,N] = A[Mpad,K]bf16 @ Bt[Npad,K]^T ; BM=128, BK=64; T2 swizzle both-sides (rule #21).
// STATS: per-block column sum/sumsq of acc (fp32, pre-rounding) -> global atomics.
// Pad rows of A MUST be zeroed when STATS=true.
template<int WM, int WN, int BNt, bool OUTBF, bool STATS>
__global__ __launch_bounds__(256) void gemm_bf16_kernel(
        const ushort_t* __restrict__ A, const ushort_t* __restrict__ Bt,
        void* __restrict__ C, int M, int N, int K, int ldc,
        float* __restrict__ colsum, float* __restrict__ colsumsq) {
    constexpr int BM = 128;
    constexpr int SM = BM / WM;
    constexpr int SN = BNt / WN;
    constexpr int MFR = SM / 16;
    constexpr int NFR = SN / 16;
    constexpr int AR = (BM * 128) / 4096;
    constexpr int BR = (BNt * 128) / 4096;

    __shared__ __align__(16) char smem[(BM + BNt) * 128];
    char* Asm = smem;
    char* Bsm = smem + BM * 128;

    const int tid = threadIdx.x;
    const int l = tid & 63;
    const int w = tid >> 6;
    const int wm = w / WN, wn = w % WN;
    const int m0 = blockIdx.y * BM;
    const int n0 = blockIdx.x * BNt;

    f32x4_t acc[MFR][NFR];
    #pragma unroll
    for (int mi = 0; mi < MFR; ++mi)
        #pragma unroll
        for (int ni = 0; ni < NFR; ++ni)
            acc[mi][ni] = (f32x4_t){0.f, 0.f, 0.f, 0.f};

    const int lrow = l >> 3;
    const int pchunk = l & 7;

    for (int k0 = 0; k0 < K; k0 += 64) {
        #pragma unroll
        for (int g = 0; g < AR; ++g) {
            int lr = g * 32 + w * 8 + lrow;
            int lchunk = pchunk ^ (lr & 7);
            gld16((const char*)A + ((size_t)(m0 + lr) * K + k0 + lchunk * 8) * 2,
                  Asm + (g * 32 + w * 8) * 128);
        }
        #pragma unroll
        for (int g = 0; g < BR; ++g) {
            int lr = g * 32 + w * 8 + lrow;
            int lchunk = pchunk ^ (lr & 7);
            gld16((const char*)Bt + ((size_t)(n0 + lr) * K + k0 + lchunk * 8) * 2,
                  Bsm + (g * 32 + w * 8) * 128);
        }
        __syncthreads();

        #pragma unroll
        for (int kk = 0; kk < 2; ++kk) {
            bf16x8_t af[MFR], bfr[NFR];
            #pragma unroll
            for (int mi = 0; mi < MFR; ++mi) {
                int ar = wm * SM + mi * 16 + (l & 15);
                int lchunk = (kk * 4 + (l >> 4)) ^ (ar & 7);
                af[mi] = *reinterpret_cast<const bf16x8_t*>(Asm + ar * 128 + lchunk * 16);
            }
            #pragma unroll
            for (int ni = 0; ni < NFR; ++ni) {
                int br = wn * SN + ni * 16 + (l & 15);
                int lchunk = (kk * 4 + (l >> 4)) ^ (br & 7);
                bfr[ni] = *reinterpret_cast<const bf16x8_t*>(Bsm + br * 128 + lchunk * 16);
            }
            #pragma unroll
            for (int mi = 0; mi < MFR; ++mi)
                #pragma unroll
                for (int ni = 0; ni < NFR; ++ni)
                    acc[mi][ni] = __builtin_amdgcn_mfma_f32_16x16x32_bf16(
                        af[mi], bfr[ni], acc[mi][ni], 0, 0, 0);
        }
        __syncthreads();
    }

    // C-write: D row=(lane>>4)*4+reg, col=lane&15 (m89-verified)
    #pragma unroll
    for (int mi = 0; mi < MFR; ++mi) {
        #pragma unroll
        for (int r = 0; r < 4; ++r) {
            int row = m0 + wm * SM + mi * 16 + (l >> 4) * 4 + r;
            if (row >= M) continue;
            #pragma unroll
            for (int ni = 0; ni < NFR; ++ni) {
                int col = n0 + wn * SN + ni * 16 + (l & 15);
                if (col < N) {
                    float v = acc[mi][ni][r];
                    if (OUTBF)
                        ((ushort_t*)C)[(size_t)row * ldc + col] = (ushort_t)rne16(v);
                    else
                        ((float*)C)[(size_t)row * ldc + col] = v;
                }
            }
        }
    }

    if (STATS) {
        // per-block column partials; pad rows contribute 0 (A pads zeroed by caller)
        float* sSum = (float*)smem;       // [BNt]
        float* sSq = sSum + BNt;          // [BNt]
        for (int i = tid; i < 2 * BNt; i += 256) sSum[i] = 0.f;
        __syncthreads();
        #pragma unroll
        for (int ni = 0; ni < NFR; ++ni) {
            float s = 0.f, q = 0.f;
            #pragma unroll
            for (int mi = 0; mi < MFR; ++mi)
                #pragma unroll
                for (int r = 0; r < 4; ++r) {
                    float v = acc[mi][ni][r];
                    s += v;
                    q += v * v;
                }
            s += __shfl_xor(s, 16, 64); q += __shfl_xor(q, 16, 64);
            s += __shfl_xor(s, 32, 64); q += __shfl_xor(q, 32, 64);
            if ((l >> 4) == 0) {
                int c = wn * SN + ni * 16 + (l & 15);
                atomicAdd(&sSum[c], s);
                atomicAdd(&sSq[c], q);
            }
        }
        __syncthreads();
        if (tid < BNt) {
            atomicAdd(&colsum[n0 + tid], sSum[tid]);
            atomicAdd(&colsumsq[n0 + tid], sSq[tid]);
        }
    }
}

// ---------------- BatchNorm ----------------
__global__ void colstats_f32_kernel(const float* __restrict__ X, int C, int rows_per_block,
                                    float* __restrict__ colsum, float* __restrict__ colsumsq) {
    int col = blockIdx.y * 256 + threadIdx.x;
    if (col >= C) return;
    int r0 = blockIdx.x * rows_per_block;
    int r1 = min(r0 + rows_per_block, NN);
    float s = 0.f, ss = 0.f;
    for (int r = r0; r < r1; ++r) {
        float v = X[(size_t)r * C + col];
        s += v;
        ss += v * v;
    }
    atomicAdd(&colsum[col], s);
    atomicAdd(&colsumsq[col], ss);
}

__global__ void finalize_stats_kernel(const float* __restrict__ colsum,
                                      const float* __restrict__ colsumsq,
                                      float* __restrict__ meanv, float* __restrict__ rstdv,
                                      int C) {
    int c = blockIdx.x * 256 + threadIdx.x;
    if (c >= C) return;
    float mu = colsum[c] * (1.0f / NN);
    float var = colsumsq[c] * (1.0f / NN) - mu * mu;
    meanv[c] = mu;
    rstdv[c] = rsqrtf(var + BN_EPS);
}

// in-place BN(+ReLU) on bf16 [NN][C]; optionally also write fp32 copy (layer-2 -> x6)
template<bool RELU>
__global__ void bn_bf16_kernel(ushort_t* __restrict__ Y, float* __restrict__ f32out,
                               const float* __restrict__ meanv, const float* __restrict__ rstdv,
                               const float* __restrict__ g, const float* __restrict__ be, int C) {
    long long i = (long long)blockIdx.x * 256 + threadIdx.x;
    long long tot = (long long)NN * (C / 8);
    if (i >= tot) return;
    int c0 = (int)(i % (C / 8)) * 8;
    uint4 v = reinterpret_cast<const uint4*>(Y)[i];
    float f[8];
    f[0] = u2f(v.x << 16); f[1] = u2f(v.x & 0xFFFF0000u);
    f[2] = u2f(v.y << 16); f[3] = u2f(v.y & 0xFFFF0000u);
    f[4] = u2f(v.z << 16); f[5] = u2f(v.z & 0xFFFF0000u);
    f[6] = u2f(v.w << 16); f[7] = u2f(v.w & 0xFFFF0000u);
    #pragma unroll
    for (int j = 0; j < 8; ++j) {
        float y = g[c0 + j] * (f[j] - meanv[c0 + j]) * rstdv[c0 + j] + be[c0 + j];
        if (RELU) y = fmaxf(y, 0.f);
        f[j] = y;
    }
    uint4 o;
    o.x = pack2(f[0], f[1]); o.y = pack2(f[2], f[3]);
    o.z = pack2(f[4], f[5]); o.w = pack2(f[6], f[7]);
    reinterpret_cast<uint4*>(Y)[i] = o;
    if (f32out) {
        long long row = i / (C / 8);
        float* p = f32out + row * C + c0;
        reinterpret_cast<float4*>(p)[0] = make_float4(f[0], f[1], f[2], f[3]);
        reinterpret_cast<float4*>(p)[1] = make_float4(f[4], f[5], f[6], f[7]);
    }
}

template<bool RELU, int C>
__global__ void bn_f32_kernel(const float* __restrict__ X, float* __restrict__ Y,
                              const float* __restrict__ meanv, const float* __restrict__ rstdv,
                              const float* __restrict__ g, const float* __restrict__ be) {
    const long long TOT = (long long)NN * (C / 4);
    long long i = (long long)blockIdx.x * 256 + threadIdx.x;
    if (i >= TOT) return;
    int c = (int)((i % (C / 4)) * 4);
    float4 v = reinterpret_cast<const float4*>(X)[i];
    float r[4] = {v.x, v.y, v.z, v.w};
    #pragma unroll
    for (int j = 0; j < 4; ++j) {
        float y = g[c + j] * (r[j] - meanv[c + j]) * rstdv[c + j] + be[c + j];
        if (RELU) y = fmaxf(y, 0.f);
        r[j] = y;
    }
    reinterpret_cast<float4*>(Y)[i] = make_float4(r[0], r[1], r[2], r[3]);
}

// ---------------- orchestration ----------------
extern "C" void kernel_launch(void* const* d_in, const int* in_sizes, int n_in,
                              void* d_out, int out_size, void* d_ws, size_t ws_size,
                              hipStream_t stream) {
    const float* x   = (const float*)d_in[0];
    const int*   ei  = (const int*)d_in[1];
    const float* W1  = (const float*)d_in[2];
    const float* g1  = (const float*)d_in[4];
    const float* be1 = (const float*)d_in[5];
    const float* W2  = (const float*)d_in[6];
    const float* g2  = (const float*)d_in[8];
    const float* be2 = (const float*)d_in[9];
    const float* W3  = (const float*)d_in[10];
    const float* g3  = (const float*)d_in[12];
    const float* be3 = (const float*)d_in[13];

    const int* src = ei;
    const int* dst = ei + NE;

    float* out = (float*)d_out;                 // [NN, 40]
    float* x6  = out + (size_t)NN * NCLS;       // [NN, 512] fp32 second output

    char* wp = (char*)d_ws;
    size_t o = 0;
    auto take = [&](size_t bytes) { char* p = wp + o; o = (o + bytes + 255) & ~(size_t)255; return p; };
    float*    dinv     = (float*)take((size_t)NN * 4);
    int*      degi     = (int*)take((size_t)NN * 4);
    int*      rowptr   = (int*)take((size_t)NN * 4);
    int*      cursor   = (int*)take((size_t)NN * 4);
    int*      bsum     = (int*)take(512 * 4);
    int*      boff     = (int*)take(512 * 4);
    float*    colsum   = (float*)take(512 * 4);
    float*    colsumsq = (float*)take(512 * 4);
    float*    meanv    = (float*)take(512 * 4);
    float*    rstdv    = (float*)take(512 * 4);
    int*      csr_src  = (int*)take((size_t)NE * 4);
    float*    csr_w    = (float*)take((size_t)NE * 4);
    ushort_t* W1t      = (ushort_t*)take((size_t)512 * 128 * 2);
    ushort_t* W2t      = (ushort_t*)take((size_t)512 * 512 * 2);
    ushort_t* W3t      = (ushort_t*)take((size_t)64 * 512 * 2);
    ushort_t* xb       = (ushort_t*)take((size_t)NN * FIN * 2);
    ushort_t* aggX1b   = (ushort_t*)take((size_t)MPAD * FIN * 2);
    ushort_t* y1b      = (ushort_t*)take((size_t)MPAD * HIDD * 2);   // raw gemm1 out
    ushort_t* aggX3b   = (ushort_t*)take((size_t)MPAD * HIDD * 2);
    ushort_t* y2b      = (ushort_t*)take((size_t)MPAD * HIDD * 2);   // gemm2 out -> x6b (in-place BN)
    float*    h3       = (float*)take((size_t)NN * NCLS * 4);
    float*    agg3     = (float*)take((size_t)NN * NCLS * 4);

    const int B = 256;
    const int NB = ceil_div_ll(NN, 256);
    const int MG = MPAD / 128;  // 782

    // --- CSR build ---
    hipMemsetAsync(degi, 0, (size_t)NN * 4, stream);
    deg_int_kernel<<<ceil_div_ll(NE, B), B, 0, stream>>>(dst, degi);
    dinv_from_deg_kernel<<<NB, B, 0, stream>>>(degi, dinv);
    scan_block_kernel<<<NB, B, 0, stream>>>(degi, rowptr, bsum);
    scan_bsum_kernel<<<1, 512, 0, stream>>>(bsum, boff, NB);
    add_offsets_kernel<<<NB, B, 0, stream>>>(rowptr, boff, cursor);
    scatter_kernel<<<ceil_div_ll(NE, B), B, 0, stream>>>(src, dst, dinv, cursor, csr_src, csr_w);

    // --- weight prep + x->bf16 + pad-row zeroing (STATS requires zero A pads) ---
    transpose_w_kernel<<<ceil_div_ll(512 * 128, B), B, 0, stream>>>(W1, W1t, 128, 512, 512);
    transpose_w_kernel<<<ceil_div_ll(512 * 512, B), B, 0, stream>>>(W2, W2t, 512, 512, 512);
    transpose_w_kernel<<<ceil_div_ll(64 * 512, B), B, 0, stream>>>(W3, W3t, 512, 40, 64);
    f32_to_bf16_kernel<<<ceil_div_ll((long long)NN * FIN / 8, B), B, 0, stream>>>(
        x, (unsigned*)xb, (long long)NN * FIN / 8);
    hipMemsetAsync(aggX1b + (size_t)NN * FIN, 0, (size_t)(MPAD - NN) * FIN * 2, stream);
    hipMemsetAsync(aggX3b + (size_t)NN * HIDD, 0, (size_t)(MPAD - NN) * HIDD * 2, stream);

    // --- layer 1: agg(xb) -> GEMM(K=128, fused stats) -> finalize ---
    agg_csr128b_kernel<<<ceil_div_ll(NN, 4), B, 0, stream>>>(xb, rowptr, degi, dinv, csr_src, csr_w, aggX1b);
    hipMemsetAsync(colsum, 0, 4096, stream);
    {
        dim3 grid(HIDD / 128, MG);
        gemm_bf16_kernel<2, 2, 128, true, true><<<grid, B, 0, stream>>>(
            aggX1b, W1t, y1b, NN, HIDD, FIN, HIDD, colsum, colsumsq);
    }
    finalize_stats_kernel<<<2, B, 0, stream>>>(colsum, colsumsq, meanv, rstdv, HIDD);

    // --- layer 2: gather with fused BN+ReLU(y1b) -> GEMM(K=512, fused stats) -> BN+ReLU -> x6 ---
    agg_bn512_kernel<<<ceil_div_ll(NN, 4), B, 0, stream>>>(
        y1b, rowptr, degi, dinv, csr_src, csr_w, meanv, rstdv, g1, be1, aggX3b);
    hipMemsetAsync(colsum, 0, 4096, stream);
    {
        dim3 grid(HIDD / 128, MG);
        gemm_bf16_kernel<2, 2, 128, true, true><<<grid, B, 0, stream>>>(
            aggX3b, W2t, y2b, NN, HIDD, HIDD, HIDD, colsum, colsumsq);
    }
    finalize_stats_kernel<<<2, B, 0, stream>>>(colsum, colsumsq, meanv, rstdv, HIDD);
    bn_bf16_kernel<true><<<ceil_div_ll((long long)NN * HIDD / 8, B), B, 0, stream>>>(
        y2b, x6, meanv, rstdv, g2, be2, HIDD);  // y2b = x6 bf16; x6 fp32 -> d_out

    // --- layer 3: GEMM(N=40) -> agg -> BN ---
    {
        dim3 grid(1, MG);
        gemm_bf16_kernel<4, 1, 64, false, false><<<grid, B, 0, stream>>>(
            y2b, W3t, h3, NN, NCLS, HIDD, NCLS, nullptr, nullptr);
    }
    agg_csr40_kernel<<<ceil_div_ll(NN, 4), B, 0, stream>>>(h3, rowptr, degi, dinv, csr_src, csr_w, agg3);
    hipMemsetAsync(colsum, 0, 4096, stream);
    {
        dim3 grid(ceil_div_ll(NN, 128), 1);
        colstats_f32_kernel<<<grid, B, 0, stream>>>(agg3, NCLS, 128, colsum, colsumsq);
    }
    finalize_stats_kernel<<<1, B, 0, stream>>>(colsum, colsumsq, meanv, rstdv, NCLS);
    bn_f32_kernel<false, NCLS><<<ceil_div_ll((long long)NN * NCLS / 4, B), B, 0, stream>>>(
        agg3, out, meanv, rstdv, g3, be3);
}